// Round 1
// baseline (202.876 us; speedup 1.0000x reference)
//
#include <hip/hip_runtime.h>
#include <hip/hip_bf16.h>

typedef unsigned int u32;
typedef unsigned short u16;
typedef __attribute__((ext_vector_type(8))) __bf16 bf8v;
typedef __attribute__((ext_vector_type(16))) float f32x16;
typedef __attribute__((ext_vector_type(8))) u16 u16x8;

// float -> bf16 round-to-nearest-even
__device__ inline u16 f2bf(float f) {
    u32 u = __float_as_uint(f);
    u = (u + 0x7FFF + ((u >> 16) & 1)) >> 16;
    return (u16)u;
}
__device__ inline u32 pk2(float a, float b) {
    return (u32)f2bf(a) | ((u32)f2bf(b) << 16);
}
__device__ inline float bf2f(u16 h) { return __uint_as_float(((u32)h) << 16); }

// async global->LDS DMA, 16B/lane; LDS dest = wave-uniform base + lane*16
__device__ inline void dma16(const u16* g, u16* l) {
    __builtin_amdgcn_global_load_lds(
        (const __attribute__((address_space(1))) void*)g,
        (__attribute__((address_space(3))) void*)l, 16, 0, 0);
}

// ---------------- fused input conversion ----------------
// blk < 2048: x fp32 -> packed tiles xp[t=row/32][c=d/8][row%32][8]
// blk >= 2048: W fp32 -> bf16, chunk-XOR-swizzled rows:
//   wall[m][row][cs=c^(row&7)][8]  (so LDS-linear DMA + conflict-free ds_read)
__global__ void cvt_all(const float* __restrict__ x,
                        const float* __restrict__ wq, const float* __restrict__ wk,
                        const float* __restrict__ wv,
                        u16* __restrict__ xp, u16* __restrict__ wall) {
    const int blk = blockIdx.x;
    if (blk < 2048) {
        int g = blk * 256 + threadIdx.x;
        int row = g >> 5, cp = g & 31;
        const float* s = x + row * 256 + cp * 8;
        float4 a = *(const float4*)s;
        float4 b = *(const float4*)(s + 4);
        uint4 o;
        o.x = pk2(a.x, a.y); o.y = pk2(a.z, a.w);
        o.z = pk2(b.x, b.y); o.w = pk2(b.z, b.w);
        *(uint4*)(xp + (row >> 5) * 8192 + cp * 256 + (row & 31) * 8) = o;
    } else {
        const int bb = blk - 2048;                 // 0..95
        const int m = bb >> 5;
        const float* src = m == 0 ? wq : m == 1 ? wk : wv;
        int g = (bb & 31) * 256 + threadIdx.x;
        int row = g >> 5, c = g & 31;
        const float* s = src + row * 256 + c * 8;
        float4 a = *(const float4*)s;
        float4 b = *(const float4*)(s + 4);
        uint4 o;
        o.x = pk2(a.x, a.y); o.y = pk2(a.z, a.w);
        o.z = pk2(b.x, b.y); o.w = pk2(b.z, b.w);
        *(uint4*)(wall + m * 65536 + row * 256 + ((c ^ (row & 7)) * 8)) = o;
    }
}

// ---------------- QKV projection: 32x32 MFMA, W staged in LDS ----------------
// grid 1536 (XCD-aware), block 256 = 4 waves x 32 rows (128-row x-tile, 64 cols).
// Q,K packed: [t=n/32][c=d/8][n%32][8];  V packed: [t][kvc=(n%32)/8][d][n%8]
__global__ __launch_bounds__(256) void qkv_proj(
    const u16* __restrict__ xp, const u16* __restrict__ wall,
    const float* __restrict__ bq, const float* __restrict__ bk, const float* __restrict__ bv,
    u16* __restrict__ qp, u16* __restrict__ kp, u16* __restrict__ vp)
{
    __shared__ u16 Ws[64 * 256];   // 32 KB W tile, rows chunk-XOR-swizzled

    const int blk = blockIdx.x;
    const int xcd = blk & 7;
    const int s2 = blk >> 3;            // 0..191
    const int rt = s2 / 12;             // 0..15
    const int yz = s2 % 12;
    const int sel = yz >> 2;            // 0..2
    const int colbase = (yz & 3) * 64;
    const int rowbase0 = (xcd * 16 + rt) * 128;   // disjoint 2048-row slab per XCD

    const float* bias = sel == 0 ? bq : sel == 1 ? bk : bv;
    const int tid = threadIdx.x;
    const int wave = tid >> 6, lane = tid & 63;
    const int l31 = lane & 31, l5 = lane >> 5;
    const int tg = (rowbase0 >> 5) + wave;        // global 32-row tile index

    // stage W rows [colbase, +64) -> LDS (linear DMA, swizzle pre-applied)
    {
        const u16* wsrc = wall + sel * 65536 + colbase * 256;
#pragma unroll
        for (int j = 0; j < 8; j++) {
            const int i = wave * 8 + j;            // 32 x 1KB chunks
            dma16(wsrc + i * 512 + lane * 8, Ws + i * 512);
        }
    }
    asm volatile("s_waitcnt vmcnt(0)" ::: "memory");
    __syncthreads();

    f32x16 acc0, acc1;
#pragma unroll
    for (int j = 0; j < 16; j++) { acc0[j] = 0.f; acc1[j] = 0.f; }

    const u16* ap = xp + tg * 8192 + l5 * 256 + l31 * 8;     // coalesced 1KB/instr
    const int sw = l31 & 7;
#pragma unroll
    for (int kk = 0; kk < 16; kk++) {
        bf8v af = *(const bf8v*)(ap + kk * 512);
        bf8v b0 = *(const bf8v*)(Ws + l31 * 256 + (((kk * 2 + l5) ^ sw) * 8));
        bf8v b1 = *(const bf8v*)(Ws + (32 + l31) * 256 + (((kk * 2 + l5) ^ sw) * 8));
        acc0 = __builtin_amdgcn_mfma_f32_32x32x16_bf16(af, b0, acc0, 0, 0, 0);
        acc1 = __builtin_amdgcn_mfma_f32_32x32x16_bf16(af, b1, acc1, 0, 0, 0);
    }

    const float bias0 = bias[colbase + l31], bias1 = bias[colbase + 32 + l31];
    if (sel < 2) {
        u16* base = (sel == 0 ? qp : kp) + tg * 8192;
        const int c0 = (colbase >> 3) + (l31 >> 3), j0 = l31 & 7;
#pragma unroll
        for (int r = 0; r < 16; r++) {
            const int R = (r & 3) + 8 * (r >> 2) + 4 * l5;
            base[c0 * 256 + R * 8 + j0]       = f2bf(acc0[r] + bias0);
            base[(c0 + 4) * 256 + R * 8 + j0] = f2bf(acc1[r] + bias1);
        }
    } else {
        u16* base = vp + tg * 8192;
        const int d0 = colbase + l31, d1 = d0 + 32;
#pragma unroll
        for (int r = 0; r < 16; r++) {
            const int R = (r & 3) + 8 * (r >> 2) + 4 * l5;
            base[(R >> 3) * 2048 + d0 * 8 + (R & 7)] = f2bf(acc0[r] + bias0);
            base[(R >> 3) * 2048 + d1 * 8 + (R & 7)] = f2bf(acc1[r] + bias1);
        }
    }
}

// ---------------- flash attention: merged-phase MFMA pipeline ----------------
// grid 512 (XCD-swizzled), block 256 = 4 waves x 32 q-rows. Bc=32, D=256, S=4.
// Per iter: [vmcnt(0); barrier]; then ONE merged MFMA cluster (prio 1):
//   QK(it+1) as two 8-deep chains (c0,c1) interleaved 1:1 with the 16
//   independent PV(it) MFMAs + 2 ls MFMAs — PV issues fill the QK chain's
//   dep-latency bubbles. DMA V(it+1),K(it+2) issued after first MFMAs.
// Trailing exp/pack/ds_write cluster runs at prio 0 (other waves' MFMAs win).
// K prefetched 2 ahead, V 1 ahead; 1 barrier/iter.
__global__ __launch_bounds__(256, 2) void flash_attn(
    const u16* __restrict__ qp_, const u16* __restrict__ kp_, const u16* __restrict__ vp_,
    const float* __restrict__ scale,
    u16* __restrict__ Opb, float* __restrict__ ml)
{
    __shared__ u16 Ks[2 * 8192];   // [buf][c(32)][kv(32)][8]
    __shared__ u16 Vs[2 * 8192];   // [buf][kvc(4)][d(256)][8]
    __shared__ u16 Ps[4 * 1152];   // per-wave 32 x 36

    const int tid = threadIdx.x;
    const int wave = tid >> 6, lane = tid & 63;
    const int l31 = lane & 31, l5 = lane >> 5;

    const int blk = blockIdx.x;
    const int slot = blk >> 3;
    const int g = (blk & 7) * 2 + (slot >> 5);   // (b,s) group; matches proj's XCD slabs
    const int qtile = slot & 31;
    const int b = g >> 2, s = g & 3;
    const int qbase = qtile * 128 + wave * 32;
    const float is2 = 1.44269504088896f / scale[0];   // log2(e)/scale

    union { u16x8 u; bf8v v; } oneu;
#pragma unroll
    for (int j = 0; j < 8; j++) oneu.u[j] = 0x3F80;
    const bf8v ones = oneu.v;

    // Q frags from packed layout (coalesced)
    bf8v qf[16];
    {
        const u16* qp = qp_ + (b * 128 + qtile * 4 + wave) * 8192 + l31 * 8;
#pragma unroll
        for (int kk = 0; kk < 16; kk++)
            qf[kk] = *(const bf8v*)(qp + (kk * 2 + l5) * 256);
    }

    f32x16 o[8];
#pragma unroll
    for (int i = 0; i < 8; i++)
#pragma unroll
        for (int j = 0; j < 16; j++) o[i][j] = 0.f;
    f32x16 ls;
#pragma unroll
    for (int j = 0; j < 16; j++) ls[j] = 0.f;

    const u16* kbase = kp_ + (b * 128 + s * 32) * 8192;
    const u16* vbase = vp_ + (b * 128 + s * 32) * 8192;
    u16* pw = Ps + wave * 1152;

    // prologue: K0 (all 4 chunks FIRST so vmcnt(8) == K0 landed), then V0, K1
#pragma unroll
    for (int j = 0; j < 4; j++) {
        const int i = wave * 4 + j;
        dma16(kbase + i * 512 + lane * 8, Ks + i * 512);
    }
#pragma unroll
    for (int j = 0; j < 4; j++) {
        const int i = wave * 4 + j;
        dma16(vbase + i * 512 + lane * 8, Vs + i * 512);
    }
#pragma unroll
    for (int j = 0; j < 4; j++) {
        const int i = wave * 4 + j;
        dma16(kbase + 8192 + i * 512 + lane * 8, Ks + 8192 + i * 512);
    }
    asm volatile("s_waitcnt vmcnt(8)" ::: "memory");
    asm volatile("s_barrier" ::: "memory");

    // QK(0) -> P(0) frags (dual chains)
    bf8v pf0, pf1;
    {
        f32x16 c0, c1;
#pragma unroll
        for (int j = 0; j < 16; j++) { c0[j] = 0.f; c1[j] = 0.f; }
#pragma unroll
        for (int j = 0; j < 8; j++) {
            bf8v kf0 = *(const bf8v*)(Ks + (j * 2 + l5) * 256 + l31 * 8);
            c0 = __builtin_amdgcn_mfma_f32_32x32x16_bf16(qf[j], kf0, c0, 0, 0, 0);
            bf8v kf1 = *(const bf8v*)(Ks + ((8 + j) * 2 + l5) * 256 + l31 * 8);
            c1 = __builtin_amdgcn_mfma_f32_32x32x16_bf16(qf[8 + j], kf1, c1, 0, 0, 0);
        }
#pragma unroll
        for (int r = 0; r < 16; r++) {
            const int R = (r & 3) + 8 * (r >> 2) + 4 * l5;
            pw[R * 36 + l31] = f2bf(exp2f((c0[r] + c1[r]) * is2));
        }
        asm volatile("s_waitcnt lgkmcnt(0)" ::: "memory");
        pf0 = *(const bf8v*)(pw + l31 * 36 + l5 * 8);
        pf1 = *(const bf8v*)(pw + l31 * 36 + 16 + l5 * 8);
    }

#pragma unroll 1
    for (int it = 0; it < 31; it++) {
        const int buf = it & 1;
        asm volatile("s_waitcnt vmcnt(0)" ::: "memory");  // V(it), K(it+1) landed
        asm volatile("s_barrier" ::: "memory");           // visible; old bufs free

        const u16* Kb_ = Ks + (buf ^ 1) * 8192;           // K(it+1)
        const u16* Vb_ = Vs + buf * 8192;                 // V(it)

        __builtin_amdgcn_s_setprio(1);
        f32x16 c0, c1;
#pragma unroll
        for (int j = 0; j < 16; j++) { c0[j] = 0.f; c1[j] = 0.f; }
        // ls first: chain-serial but independent, ready at iter start
        ls = __builtin_amdgcn_mfma_f32_32x32x16_bf16(pf0, ones, ls, 0, 0, 0);
        ls = __builtin_amdgcn_mfma_f32_32x32x16_bf16(pf1, ones, ls, 0, 0, 0);

        // DMA next tiles (after first MFMAs are in flight; full iter of slack)
        {
            const u16* vt_ = vbase + (it + 1) * 8192;
#pragma unroll
            for (int j = 0; j < 4; j++) {
                const int i = wave * 4 + j;
                dma16(vt_ + i * 512 + lane * 8, Vs + (buf ^ 1) * 8192 + i * 512);
            }
            if (it < 30) {
                const u16* kt_ = kbase + (it + 2) * 8192;
#pragma unroll
                for (int j = 0; j < 4; j++) {
                    const int i = wave * 4 + j;
                    dma16(kt_ + i * 512 + lane * 8, Ks + buf * 8192 + i * 512);
                }
            }
        }

        // merged cluster: QK(it+1) dual chains 1:1 with independent PV(it)
#pragma unroll
        for (int j = 0; j < 8; j++) {
            bf8v kf0 = *(const bf8v*)(Kb_ + (j * 2 + l5) * 256 + l31 * 8);
            c0 = __builtin_amdgcn_mfma_f32_32x32x16_bf16(qf[j], kf0, c0, 0, 0, 0);
            bf8v vf0 = *(const bf8v*)(Vb_ + (l5 * 256 + j * 32 + l31) * 8);
            o[j] = __builtin_amdgcn_mfma_f32_32x32x16_bf16(pf0, vf0, o[j], 0, 0, 0);
            bf8v kf1 = *(const bf8v*)(Kb_ + ((8 + j) * 2 + l5) * 256 + l31 * 8);
            c1 = __builtin_amdgcn_mfma_f32_32x32x16_bf16(qf[8 + j], kf1, c1, 0, 0, 0);
            bf8v vf1 = *(const bf8v*)(Vb_ + ((2 + l5) * 256 + j * 32 + l31) * 8);
            o[j] = __builtin_amdgcn_mfma_f32_32x32x16_bf16(pf1, vf1, o[j], 0, 0, 0);
        }
        __builtin_amdgcn_s_setprio(0);

        // trailing exp/pack/write cluster of P(it+1), prio 0
#pragma unroll
        for (int r = 0; r < 16; r++) {
            const int R = (r & 3) + 8 * (r >> 2) + 4 * l5;
            pw[R * 36 + l31] = f2bf(exp2f((c0[r] + c1[r]) * is2));
        }
        asm volatile("s_waitcnt lgkmcnt(0)" ::: "memory");
        pf0 = *(const bf8v*)(pw + l31 * 36 + l5 * 8);
        pf1 = *(const bf8v*)(pw + l31 * 36 + 16 + l5 * 8);
    }

    // tail: PV(31)
    asm volatile("s_waitcnt vmcnt(0)" ::: "memory");
    asm volatile("s_barrier" ::: "memory");
    {
        const u16* Vb_ = Vs + 8192;   // V(31) in buf 1
        __builtin_amdgcn_s_setprio(1);
        ls = __builtin_amdgcn_mfma_f32_32x32x16_bf16(pf0, ones, ls, 0, 0, 0);
        ls = __builtin_amdgcn_mfma_f32_32x32x16_bf16(pf1, ones, ls, 0, 0, 0);
#pragma unroll
        for (int j = 0; j < 8; j++) {
            bf8v vf0 = *(const bf8v*)(Vb_ + (l5 * 256 + j * 32 + l31) * 8);
            o[j] = __builtin_amdgcn_mfma_f32_32x32x16_bf16(pf0, vf0, o[j], 0, 0, 0);
            bf8v vf1 = *(const bf8v*)(Vb_ + ((2 + l5) * 256 + j * 32 + l31) * 8);
            o[j] = __builtin_amdgcn_mfma_f32_32x32x16_bf16(pf1, vf1, o[j], 0, 0, 0);
        }
        __builtin_amdgcn_s_setprio(0);
    }

    // epilogue: unnormalized O in bf16 + l (m==0 everywhere)
    const int rowg = s * 16384 + b * 4096 + qbase;
    u16* ob = Opb + (size_t)rowg * 256;
#pragma unroll
    for (int nb = 0; nb < 8; nb++)
#pragma unroll
        for (int r = 0; r < 16; r++) {
            const int R = (r & 3) + 8 * (r >> 2) + 4 * l5;
            ob[R * 256 + nb * 32 + l31] = f2bf(o[nb][r]);
        }
    if (l31 == 0)
#pragma unroll
        for (int r = 0; r < 16; r++) {
            const int R = (r & 3) + 8 * (r >> 2) + 4 * l5;
            ml[rowg + R] = ls[r];
        }
}

// ---------------- combine partials (m==0: denom = sum of l) ----------------
__global__ __launch_bounds__(256) void combine(
    const u16* __restrict__ Opb, const float* __restrict__ ml, float* __restrict__ out)
{
    const int row = blockIdx.x * 4 + (threadIdx.x >> 6);
    const int lane = threadIdx.x & 63;
    const float denom = ml[row] + ml[16384 + row] + ml[32768 + row] + ml[49152 + row];
    float4 acc = {0.f, 0.f, 0.f, 0.f};
#pragma unroll
    for (int si = 0; si < 4; si++) {
        ushort4 v = *(const ushort4*)(Opb + ((size_t)si * 16384 + row) * 256 + lane * 4);
        acc.x += bf2f(v.x); acc.y += bf2f(v.y);
        acc.z += bf2f(v.z); acc.w += bf2f(v.w);
    }
    const float inv = 1.0f / denom;
    acc.x *= inv; acc.y *= inv; acc.z *= inv; acc.w *= inv;
    *((float4*)(out + (size_t)row * 256) + lane) = acc;
}

extern "C" void kernel_launch(void* const* d_in, const int* in_sizes, int n_in,
                              void* d_out, int out_size, void* d_ws, size_t ws_size,
                              hipStream_t stream) {
    const float* x     = (const float*)d_in[0];
    const float* Wq    = (const float*)d_in[1];
    const float* bq    = (const float*)d_in[2];
    const float* Wk    = (const float*)d_in[3];
    const float* bk    = (const float*)d_in[4];
    const float* Wv    = (const float*)d_in[5];
    const float* bv    = (const float*)d_in[6];
    const float* scale = (const float*)d_in[7];
    float* out = (float*)d_out;

    char* ws = (char*)d_ws;
    u16* xp   = (u16*)ws;                        // 8 MB packed x
    u16* qp   = (u16*)(ws + (8u  << 20));        // 8 MB packed Q
    u16* kp   = (u16*)(ws + (16u << 20));        // 8 MB packed K
    u16* vp   = (u16*)(ws + (24u << 20));        // 8 MB packed V
    u16* wall = (u16*)(ws + (32u << 20));        // 3 x 128 KB bf16 W (swizzled)
    u16* Opb  = (u16*)(ws + (34u << 20));        // 4 x 8 MB bf16 partials
    float* ml = (float*)(ws + (66u << 20));      // 4 x 64 KB l-sums

    cvt_all<<<2144, 256, 0, stream>>>(x, Wq, Wk, Wv, xp, wall);
    qkv_proj<<<1536, 256, 0, stream>>>(xp, wall, bq, bk, bv, qp, kp, vp);
    flash_attn<<<512, 256, 0, stream>>>(qp, kp, vp, scale, Opb, ml);
    combine<<<4096, 256, 0, stream>>>(Opb, ml, out);
}

// Round 2
// 182.758 us; speedup vs baseline: 1.1101x; 1.1101x over previous
//
#include <hip/hip_runtime.h>
#include <hip/hip_bf16.h>

typedef unsigned int u32;
typedef unsigned short u16;
typedef __attribute__((ext_vector_type(8))) __bf16 bf8v;
typedef __attribute__((ext_vector_type(16))) float f32x16;
typedef __attribute__((ext_vector_type(8))) u16 u16x8;

// float -> bf16 round-to-nearest-even
__device__ inline u16 f2bf(float f) {
    u32 u = __float_as_uint(f);
    u = (u + 0x7FFF + ((u >> 16) & 1)) >> 16;
    return (u16)u;
}
__device__ inline u32 pk2(float a, float b) {
    return (u32)f2bf(a) | ((u32)f2bf(b) << 16);
}
__device__ inline float bf2f(u16 h) { return __uint_as_float(((u32)h) << 16); }

// packed bf16 pair from two f32 (hardware RNE)
__device__ inline u32 cvtpk(float a, float b) {
    u32 r;
    asm("v_cvt_pk_bf16_f32 %0, %1, %2" : "=v"(r) : "v"(a), "v"(b));
    return r;
}
// exchange: a[lanes 32-63] <-> b[lanes 0-31]
__device__ inline void plswap(u32& a, u32& b) {
    asm("v_permlane32_swap_b32 %0, %1" : "+v"(a), "+v"(b));
}

// async global->LDS DMA, 16B/lane; LDS dest = wave-uniform base + lane*16
__device__ inline void dma16(const u16* g, u16* l) {
    __builtin_amdgcn_global_load_lds(
        (const __attribute__((address_space(1))) void*)g,
        (__attribute__((address_space(3))) void*)l, 16, 0, 0);
}

// ---------------- fused input conversion ----------------
// blk < 2048: x fp32 -> packed tiles xp[t=row/32][c=d/8][row%32][8]
// blk >= 2048: W fp32 -> bf16, chunk-XOR-swizzled rows:
//   wall[m][row][cs=c^(row&7)][8]  (so LDS-linear DMA + conflict-free ds_read)
__global__ void cvt_all(const float* __restrict__ x,
                        const float* __restrict__ wq, const float* __restrict__ wk,
                        const float* __restrict__ wv,
                        u16* __restrict__ xp, u16* __restrict__ wall) {
    const int blk = blockIdx.x;
    if (blk < 2048) {
        int g = blk * 256 + threadIdx.x;
        int row = g >> 5, cp = g & 31;
        const float* s = x + row * 256 + cp * 8;
        float4 a = *(const float4*)s;
        float4 b = *(const float4*)(s + 4);
        uint4 o;
        o.x = pk2(a.x, a.y); o.y = pk2(a.z, a.w);
        o.z = pk2(b.x, b.y); o.w = pk2(b.z, b.w);
        *(uint4*)(xp + (row >> 5) * 8192 + cp * 256 + (row & 31) * 8) = o;
    } else {
        const int bb = blk - 2048;                 // 0..95
        const int m = bb >> 5;
        const float* src = m == 0 ? wq : m == 1 ? wk : wv;
        int g = (bb & 31) * 256 + threadIdx.x;
        int row = g >> 5, c = g & 31;
        const float* s = src + row * 256 + c * 8;
        float4 a = *(const float4*)s;
        float4 b = *(const float4*)(s + 4);
        uint4 o;
        o.x = pk2(a.x, a.y); o.y = pk2(a.z, a.w);
        o.z = pk2(b.x, b.y); o.w = pk2(b.z, b.w);
        *(uint4*)(wall + m * 65536 + row * 256 + ((c ^ (row & 7)) * 8)) = o;
    }
}

// ---------------- QKV projection: 32x32 MFMA, W staged in LDS ----------------
// grid 1536 (XCD-aware), block 256 = 4 waves x 32 rows (128-row x-tile, 64 cols).
// Q,K packed: [t=n/32][c=d/8][n%32][8];  V packed: [t][kvc=(n%32)/8][d][n%8]
__global__ __launch_bounds__(256) void qkv_proj(
    const u16* __restrict__ xp, const u16* __restrict__ wall,
    const float* __restrict__ bq, const float* __restrict__ bk, const float* __restrict__ bv,
    u16* __restrict__ qp, u16* __restrict__ kp, u16* __restrict__ vp)
{
    __shared__ u16 Ws[64 * 256];   // 32 KB W tile, rows chunk-XOR-swizzled

    const int blk = blockIdx.x;
    const int xcd = blk & 7;
    const int s2 = blk >> 3;            // 0..191
    const int rt = s2 / 12;             // 0..15
    const int yz = s2 % 12;
    const int sel = yz >> 2;            // 0..2
    const int colbase = (yz & 3) * 64;
    const int rowbase0 = (xcd * 16 + rt) * 128;   // disjoint 2048-row slab per XCD

    const float* bias = sel == 0 ? bq : sel == 1 ? bk : bv;
    const int tid = threadIdx.x;
    const int wave = tid >> 6, lane = tid & 63;
    const int l31 = lane & 31, l5 = lane >> 5;
    const int tg = (rowbase0 >> 5) + wave;        // global 32-row tile index

    // stage W rows [colbase, +64) -> LDS (linear DMA, swizzle pre-applied)
    {
        const u16* wsrc = wall + sel * 65536 + colbase * 256;
#pragma unroll
        for (int j = 0; j < 8; j++) {
            const int i = wave * 8 + j;            // 32 x 1KB chunks
            dma16(wsrc + i * 512 + lane * 8, Ws + i * 512);
        }
    }
    asm volatile("s_waitcnt vmcnt(0)" ::: "memory");
    __syncthreads();

    f32x16 acc0, acc1;
#pragma unroll
    for (int j = 0; j < 16; j++) { acc0[j] = 0.f; acc1[j] = 0.f; }

    const u16* ap = xp + tg * 8192 + l5 * 256 + l31 * 8;     // coalesced 1KB/instr
    const int sw = l31 & 7;
#pragma unroll
    for (int kk = 0; kk < 16; kk++) {
        bf8v af = *(const bf8v*)(ap + kk * 512);
        bf8v b0 = *(const bf8v*)(Ws + l31 * 256 + (((kk * 2 + l5) ^ sw) * 8));
        bf8v b1 = *(const bf8v*)(Ws + (32 + l31) * 256 + (((kk * 2 + l5) ^ sw) * 8));
        acc0 = __builtin_amdgcn_mfma_f32_32x32x16_bf16(af, b0, acc0, 0, 0, 0);
        acc1 = __builtin_amdgcn_mfma_f32_32x32x16_bf16(af, b1, acc1, 0, 0, 0);
    }

    const float bias0 = bias[colbase + l31], bias1 = bias[colbase + 32 + l31];
    if (sel < 2) {
        u16* base = (sel == 0 ? qp : kp) + tg * 8192;
        const int c0 = (colbase >> 3) + (l31 >> 3), j0 = l31 & 7;
#pragma unroll
        for (int r = 0; r < 16; r++) {
            const int R = (r & 3) + 8 * (r >> 2) + 4 * l5;
            base[c0 * 256 + R * 8 + j0]       = f2bf(acc0[r] + bias0);
            base[(c0 + 4) * 256 + R * 8 + j0] = f2bf(acc1[r] + bias1);
        }
    } else {
        u16* base = vp + tg * 8192;
        const int d0 = colbase + l31, d1 = d0 + 32;
#pragma unroll
        for (int r = 0; r < 16; r++) {
            const int R = (r & 3) + 8 * (r >> 2) + 4 * l5;
            base[(R >> 3) * 2048 + d0 * 8 + (R & 7)] = f2bf(acc0[r] + bias0);
            base[(R >> 3) * 2048 + d1 * 8 + (R & 7)] = f2bf(acc1[r] + bias1);
        }
    }
}

// ---------------- flash attention: phase-fused MFMA pipeline, in-register P ----
// grid 512 (XCD-swizzled), block 256 = 4 waves x 32 q-rows. Bc=32, D=256, S=4.
// Per iter: [vmcnt(0); barrier; DMA V(it+1),K(it+2)];
//   phase A: QK(it+1) SWAPPED (mfma(K,Q): out col = q-row) as dual 8-deep chains;
//   phase B: PV(it)+ls 18 MFMAs source-interleaved with exp2 of P(it+1) — VALU
//            runs in the MFMA pipe's shadow (round-0 structure, known good);
//   tail: 8 cvt_pk + 4 permlane32_swap build pf0/pf1 A-frags IN-REGISTER —
//         no Ps LDS, no ds_write/lgkmcnt(0)/ds_read roundtrip per iteration.
// K prefetched 2 ahead, V 1 ahead; 1 barrier/iter.
__global__ __launch_bounds__(256, 2) void flash_attn(
    const u16* __restrict__ qp_, const u16* __restrict__ kp_, const u16* __restrict__ vp_,
    const float* __restrict__ scale,
    u16* __restrict__ Opb, float* __restrict__ ml)
{
    __shared__ u16 Ks[2 * 8192];   // [buf][c(32)][kv(32)][8]
    __shared__ u16 Vs[2 * 8192];   // [buf][kvc(4)][d(256)][8]

    const int tid = threadIdx.x;
    const int wave = tid >> 6, lane = tid & 63;
    const int l31 = lane & 31, l5 = lane >> 5;

    const int blk = blockIdx.x;
    const int slot = blk >> 3;
    const int g = (blk & 7) * 2 + (slot >> 5);   // (b,s) group; matches proj's XCD slabs
    const int qtile = slot & 31;
    const int b = g >> 2, s = g & 3;
    const int qbase = qtile * 128 + wave * 32;
    const float is2 = 1.44269504088896f / scale[0];   // log2(e)/scale

    union { u16x8 u; bf8v v; } oneu;
#pragma unroll
    for (int j = 0; j < 8; j++) oneu.u[j] = 0x3F80;
    const bf8v ones = oneu.v;

    // Q frags from packed layout (coalesced); used as MFMA *B* operand (same
    // register layout as A: lane -> (index=l31, k=8*l5+j))
    bf8v qf[16];
    {
        const u16* qp = qp_ + (b * 128 + qtile * 4 + wave) * 8192 + l31 * 8;
#pragma unroll
        for (int kk = 0; kk < 16; kk++)
            qf[kk] = *(const bf8v*)(qp + (kk * 2 + l5) * 256);
    }

    f32x16 o[8];
#pragma unroll
    for (int i = 0; i < 8; i++)
#pragma unroll
        for (int j = 0; j < 16; j++) o[i][j] = 0.f;
    f32x16 ls;
#pragma unroll
    for (int j = 0; j < 16; j++) ls[j] = 0.f;

    const u16* kbase = kp_ + (b * 128 + s * 32) * 8192;
    const u16* vbase = vp_ + (b * 128 + s * 32) * 8192;

    // prologue: K0 (all 4 chunks FIRST so vmcnt(8) == K0 landed), then V0, K1
#pragma unroll
    for (int j = 0; j < 4; j++) {
        const int i = wave * 4 + j;
        dma16(kbase + i * 512 + lane * 8, Ks + i * 512);
    }
#pragma unroll
    for (int j = 0; j < 4; j++) {
        const int i = wave * 4 + j;
        dma16(vbase + i * 512 + lane * 8, Vs + i * 512);
    }
#pragma unroll
    for (int j = 0; j < 4; j++) {
        const int i = wave * 4 + j;
        dma16(kbase + 8192 + i * 512 + lane * 8, Ks + 8192 + i * 512);
    }
    asm volatile("s_waitcnt vmcnt(8)" ::: "memory");
    asm volatile("s_barrier" ::: "memory");

    // QK(0) swapped -> P(0) A-frags in-register
    bf8v pf0, pf1;
    {
        f32x16 c0, c1;
#pragma unroll
        for (int j = 0; j < 16; j++) { c0[j] = 0.f; c1[j] = 0.f; }
#pragma unroll
        for (int j = 0; j < 8; j++) {
            bf8v kf0 = *(const bf8v*)(Ks + (j * 2 + l5) * 256 + l31 * 8);
            c0 = __builtin_amdgcn_mfma_f32_32x32x16_bf16(kf0, qf[j], c0, 0, 0, 0);
            bf8v kf1 = *(const bf8v*)(Ks + ((8 + j) * 2 + l5) * 256 + l31 * 8);
            c1 = __builtin_amdgcn_mfma_f32_32x32x16_bf16(kf1, qf[8 + j], c1, 0, 0, 0);
        }
        float e[16];
#pragma unroll
        for (int r = 0; r < 16; r++)
            e[r] = __builtin_amdgcn_exp2f((c0[r] + c1[r]) * is2);
        u32 pA = cvtpk(e[0], e[1]), pB = cvtpk(e[2], e[3]);
        u32 pC = cvtpk(e[4], e[5]), pD = cvtpk(e[6], e[7]);
        plswap(pA, pC); plswap(pB, pD);
        u32 pE = cvtpk(e[8], e[9]),  pF = cvtpk(e[10], e[11]);
        u32 pG = cvtpk(e[12], e[13]), pH = cvtpk(e[14], e[15]);
        plswap(pE, pG); plswap(pF, pH);
        union { uint4 u; bf8v v; } u0, u1;
        u0.u = (uint4){pA, pB, pC, pD};
        u1.u = (uint4){pE, pF, pG, pH};
        pf0 = u0.v; pf1 = u1.v;
    }

#pragma unroll 1
    for (int it = 0; it < 31; it++) {
        const int buf = it & 1;
        asm volatile("s_waitcnt vmcnt(0)" ::: "memory");  // V(it), K(it+1) landed
        asm volatile("s_barrier" ::: "memory");           // visible; old bufs free
        {
            const u16* vt_ = vbase + (it + 1) * 8192;
#pragma unroll
            for (int j = 0; j < 4; j++) {
                const int i = wave * 4 + j;
                dma16(vt_ + i * 512 + lane * 8, Vs + (buf ^ 1) * 8192 + i * 512);
            }
            if (it < 30) {
                const u16* kt_ = kbase + (it + 2) * 8192;
#pragma unroll
                for (int j = 0; j < 4; j++) {
                    const int i = wave * 4 + j;
                    dma16(kt_ + i * 512 + lane * 8, Ks + buf * 8192 + i * 512);
                }
            }
        }
        // ---- phase A: QK(it+1) swapped, dual 8-deep accumulator chains
        const u16* Kb_ = Ks + (buf ^ 1) * 8192;
        f32x16 c0, c1;
#pragma unroll
        for (int j = 0; j < 16; j++) { c0[j] = 0.f; c1[j] = 0.f; }
#pragma unroll
        for (int j = 0; j < 8; j++) {
            bf8v kf0 = *(const bf8v*)(Kb_ + (j * 2 + l5) * 256 + l31 * 8);
            c0 = __builtin_amdgcn_mfma_f32_32x32x16_bf16(kf0, qf[j], c0, 0, 0, 0);
            bf8v kf1 = *(const bf8v*)(Kb_ + ((8 + j) * 2 + l5) * 256 + l31 * 8);
            c1 = __builtin_amdgcn_mfma_f32_32x32x16_bf16(kf1, qf[8 + j], c1, 0, 0, 0);
        }
        // ---- phase B: PV(it)+ls MFMAs interleaved with exp2 of P(it+1)
        const u16* Vb_ = Vs + buf * 8192;
        ls = __builtin_amdgcn_mfma_f32_32x32x16_bf16(pf0, ones, ls, 0, 0, 0);
        ls = __builtin_amdgcn_mfma_f32_32x32x16_bf16(pf1, ones, ls, 0, 0, 0);
        float e[16];
#pragma unroll
        for (int j = 0; j < 8; j++) {
            bf8v vf0 = *(const bf8v*)(Vb_ + (l5 * 256 + j * 32 + l31) * 8);
            o[j] = __builtin_amdgcn_mfma_f32_32x32x16_bf16(pf0, vf0, o[j], 0, 0, 0);
            e[2 * j] = __builtin_amdgcn_exp2f((c0[2 * j] + c1[2 * j]) * is2);
            bf8v vf1 = *(const bf8v*)(Vb_ + ((2 + l5) * 256 + j * 32 + l31) * 8);
            o[j] = __builtin_amdgcn_mfma_f32_32x32x16_bf16(pf1, vf1, o[j], 0, 0, 0);
            e[2 * j + 1] = __builtin_amdgcn_exp2f((c0[2 * j + 1] + c1[2 * j + 1]) * is2);
        }
        // ---- tail: build P(it+1) A-frags in-register (no LDS roundtrip)
        {
            u32 pA = cvtpk(e[0], e[1]), pB = cvtpk(e[2], e[3]);
            u32 pC = cvtpk(e[4], e[5]), pD = cvtpk(e[6], e[7]);
            plswap(pA, pC); plswap(pB, pD);
            u32 pE = cvtpk(e[8], e[9]),  pF = cvtpk(e[10], e[11]);
            u32 pG = cvtpk(e[12], e[13]), pH = cvtpk(e[14], e[15]);
            plswap(pE, pG); plswap(pF, pH);
            union { uint4 u; bf8v v; } u0, u1;
            u0.u = (uint4){pA, pB, pC, pD};
            u1.u = (uint4){pE, pF, pG, pH};
            pf0 = u0.v; pf1 = u1.v;
        }
    }

    // tail: PV(31)
    asm volatile("s_waitcnt vmcnt(0)" ::: "memory");
    asm volatile("s_barrier" ::: "memory");
    {
        const u16* Vb_ = Vs + 8192;   // V(31) in buf 1
        ls = __builtin_amdgcn_mfma_f32_32x32x16_bf16(pf0, ones, ls, 0, 0, 0);
        ls = __builtin_amdgcn_mfma_f32_32x32x16_bf16(pf1, ones, ls, 0, 0, 0);
#pragma unroll
        for (int j = 0; j < 8; j++) {
            bf8v vf0 = *(const bf8v*)(Vb_ + (l5 * 256 + j * 32 + l31) * 8);
            o[j] = __builtin_amdgcn_mfma_f32_32x32x16_bf16(pf0, vf0, o[j], 0, 0, 0);
            bf8v vf1 = *(const bf8v*)(Vb_ + ((2 + l5) * 256 + j * 32 + l31) * 8);
            o[j] = __builtin_amdgcn_mfma_f32_32x32x16_bf16(pf1, vf1, o[j], 0, 0, 0);
        }
    }

    // epilogue: unnormalized O in bf16 + l (m==0 everywhere)
    const int rowg = s * 16384 + b * 4096 + qbase;
    u16* ob = Opb + (size_t)rowg * 256;
#pragma unroll
    for (int nb = 0; nb < 8; nb++)
#pragma unroll
        for (int r = 0; r < 16; r++) {
            const int R = (r & 3) + 8 * (r >> 2) + 4 * l5;
            ob[R * 256 + nb * 32 + l31] = f2bf(o[nb][r]);
        }
    if (l31 == 0)
#pragma unroll
        for (int r = 0; r < 16; r++) {
            const int R = (r & 3) + 8 * (r >> 2) + 4 * l5;
            ml[rowg + R] = ls[r];
        }
}

// ---------------- combine partials (m==0: denom = sum of l) ----------------
__global__ __launch_bounds__(256) void combine(
    const u16* __restrict__ Opb, const float* __restrict__ ml, float* __restrict__ out)
{
    const int row = blockIdx.x * 4 + (threadIdx.x >> 6);
    const int lane = threadIdx.x & 63;
    const float denom = ml[row] + ml[16384 + row] + ml[32768 + row] + ml[49152 + row];
    float4 acc = {0.f, 0.f, 0.f, 0.f};
#pragma unroll
    for (int si = 0; si < 4; si++) {
        ushort4 v = *(const ushort4*)(Opb + ((size_t)si * 16384 + row) * 256 + lane * 4);
        acc.x += bf2f(v.x); acc.y += bf2f(v.y);
        acc.z += bf2f(v.z); acc.w += bf2f(v.w);
    }
    const float inv = 1.0f / denom;
    acc.x *= inv; acc.y *= inv; acc.z *= inv; acc.w *= inv;
    *((float4*)(out + (size_t)row * 256) + lane) = acc;
}

extern "C" void kernel_launch(void* const* d_in, const int* in_sizes, int n_in,
                              void* d_out, int out_size, void* d_ws, size_t ws_size,
                              hipStream_t stream) {
    const float* x     = (const float*)d_in[0];
    const float* Wq    = (const float*)d_in[1];
    const float* bq    = (const float*)d_in[2];
    const float* Wk    = (const float*)d_in[3];
    const float* bk    = (const float*)d_in[4];
    const float* Wv    = (const float*)d_in[5];
    const float* bv    = (const float*)d_in[6];
    const float* scale = (const float*)d_in[7];
    float* out = (float*)d_out;

    char* ws = (char*)d_ws;
    u16* xp   = (u16*)ws;                        // 8 MB packed x
    u16* qp   = (u16*)(ws + (8u  << 20));        // 8 MB packed Q
    u16* kp   = (u16*)(ws + (16u << 20));        // 8 MB packed K
    u16* vp   = (u16*)(ws + (24u << 20));        // 8 MB packed V
    u16* wall = (u16*)(ws + (32u << 20));        // 3 x 128 KB bf16 W (swizzled)
    u16* Opb  = (u16*)(ws + (34u << 20));        // 4 x 8 MB bf16 partials
    float* ml = (float*)(ws + (66u << 20));      // 4 x 64 KB l-sums

    cvt_all<<<2144, 256, 0, stream>>>(x, Wq, Wk, Wv, xp, wall);
    qkv_proj<<<1536, 256, 0, stream>>>(xp, wall, bq, bk, bv, qp, kp, vp);
    flash_attn<<<512, 256, 0, stream>>>(qp, kp, vp, scale, Opb, ml);
    combine<<<4096, 256, 0, stream>>>(Opb, ml, out);
}

// Round 3
// 178.000 us; speedup vs baseline: 1.1398x; 1.0267x over previous
//
#include <hip/hip_runtime.h>
#include <hip/hip_bf16.h>

typedef unsigned int u32;
typedef unsigned short u16;
typedef __attribute__((ext_vector_type(8))) __bf16 bf8v;
typedef __attribute__((ext_vector_type(16))) float f32x16;
typedef __attribute__((ext_vector_type(8))) u16 u16x8;

// float -> bf16 round-to-nearest-even
__device__ inline u16 f2bf(float f) {
    u32 u = __float_as_uint(f);
    u = (u + 0x7FFF + ((u >> 16) & 1)) >> 16;
    return (u16)u;
}
__device__ inline u32 pk2(float a, float b) {
    return (u32)f2bf(a) | ((u32)f2bf(b) << 16);
}
__device__ inline float bf2f(u16 h) { return __uint_as_float(((u32)h) << 16); }

// packed bf16 pair from two f32 (hardware RNE)
__device__ inline u32 cvtpk(float a, float b) {
    u32 r;
    asm("v_cvt_pk_bf16_f32 %0, %1, %2" : "=v"(r) : "v"(a), "v"(b));
    return r;
}
// exchange: a[lanes 32-63] <-> b[lanes 0-31]
__device__ inline void plswap(u32& a, u32& b) {
    asm("v_permlane32_swap_b32 %0, %1" : "+v"(a), "+v"(b));
}

// async global->LDS DMA, 16B/lane; LDS dest = wave-uniform base + lane*16
__device__ inline void dma16(const u16* g, u16* l) {
    __builtin_amdgcn_global_load_lds(
        (const __attribute__((address_space(1))) void*)g,
        (__attribute__((address_space(3))) void*)l, 16, 0, 0);
}

// ---------------- fused input conversion ----------------
// blk < 2048: x fp32 -> packed tiles xp[t=row/32][c=d/8][row%32][8]
// blk >= 2048: W fp32 -> bf16, chunk-XOR-swizzled rows:
//   wall[m][row][cs=c^(row&7)][8]  (so LDS-linear DMA + conflict-free ds_read)
__global__ void cvt_all(const float* __restrict__ x,
                        const float* __restrict__ wq, const float* __restrict__ wk,
                        const float* __restrict__ wv,
                        u16* __restrict__ xp, u16* __restrict__ wall) {
    const int blk = blockIdx.x;
    if (blk < 2048) {
        int g = blk * 256 + threadIdx.x;
        int row = g >> 5, cp = g & 31;
        const float* s = x + row * 256 + cp * 8;
        float4 a = *(const float4*)s;
        float4 b = *(const float4*)(s + 4);
        uint4 o;
        o.x = pk2(a.x, a.y); o.y = pk2(a.z, a.w);
        o.z = pk2(b.x, b.y); o.w = pk2(b.z, b.w);
        *(uint4*)(xp + (row >> 5) * 8192 + cp * 256 + (row & 31) * 8) = o;
    } else {
        const int bb = blk - 2048;                 // 0..95
        const int m = bb >> 5;
        const float* src = m == 0 ? wq : m == 1 ? wk : wv;
        int g = (bb & 31) * 256 + threadIdx.x;
        int row = g >> 5, c = g & 31;
        const float* s = src + row * 256 + c * 8;
        float4 a = *(const float4*)s;
        float4 b = *(const float4*)(s + 4);
        uint4 o;
        o.x = pk2(a.x, a.y); o.y = pk2(a.z, a.w);
        o.z = pk2(b.x, b.y); o.w = pk2(b.z, b.w);
        *(uint4*)(wall + m * 65536 + row * 256 + ((c ^ (row & 7)) * 8)) = o;
    }
}

// ---------------- QKV projection: 32x32 MFMA, 128-col W tile in LDS ----------
// grid 768 (= exactly 3 blocks/CU, XCD-aware), block 256 = 4 waves x 32 rows.
// Each block: 128 x-rows x 128 out-cols for one of {Q,K,V}. W tile 64 KB LDS.
// Per kk: ONE global af load feeds 4 MFMAs (4 independent acc chains) — 4x the
// MFMA-per-load of the old 64-col version; xp re-read 12x -> 6x.
// Q is pre-scaled by log2e/scale here (saves 16 v_mul/iter/wave in flash).
// Q,K packed: [t=n/32][c=d/8][n%32][8];  V packed: [t][kvc=(n%32)/8][d][n%8]
__global__ __launch_bounds__(256) void qkv_proj(
    const u16* __restrict__ xp, const u16* __restrict__ wall,
    const float* __restrict__ bq, const float* __restrict__ bk, const float* __restrict__ bv,
    const float* __restrict__ scale,
    u16* __restrict__ qp, u16* __restrict__ kp, u16* __restrict__ vp)
{
    __shared__ u16 Ws[128 * 256];   // 64 KB W tile, rows chunk-XOR-swizzled

    const int blk = blockIdx.x;
    const int xcd = blk & 7;
    const int r2 = blk >> 3;            // 0..95
    const int rt = r2 / 6;              // 0..15
    const int cz = r2 % 6;
    const int sel = cz >> 1;            // 0..2
    const int colbase = (cz & 1) * 128;
    const int rowbase0 = (xcd * 16 + rt) * 128;   // disjoint 2048-row slab per XCD

    const float* bias = sel == 0 ? bq : sel == 1 ? bk : bv;
    const float qs = sel == 0 ? 1.44269504088896f / scale[0] : 1.0f;  // fold log2e/scale into Q
    const int tid = threadIdx.x;
    const int wave = tid >> 6, lane = tid & 63;
    const int l31 = lane & 31, l5 = lane >> 5;
    const int tg = (rowbase0 >> 5) + wave;        // global 32-row tile index

    // stage W rows [colbase, +128) -> LDS (linear DMA, swizzle pre-applied)
    {
        const u16* wsrc = wall + sel * 65536 + colbase * 256;
#pragma unroll
        for (int j = 0; j < 16; j++) {
            const int i = wave * 16 + j;           // 64 x 1KB chunks
            dma16(wsrc + i * 512 + lane * 8, Ws + i * 512);
        }
    }
    asm volatile("s_waitcnt vmcnt(0)" ::: "memory");
    __syncthreads();

    f32x16 acc[4];
#pragma unroll
    for (int cb = 0; cb < 4; cb++)
#pragma unroll
        for (int j = 0; j < 16; j++) acc[cb][j] = 0.f;

    const u16* ap = xp + tg * 8192 + l5 * 256 + l31 * 8;     // coalesced 1KB/instr
    const int sw = l31 & 7;
#pragma unroll
    for (int kk = 0; kk < 16; kk++) {
        bf8v af = *(const bf8v*)(ap + kk * 512);
        const int co = ((kk * 2 + l5) ^ sw) * 8;
#pragma unroll
        for (int cb = 0; cb < 4; cb++) {
            bf8v bfr = *(const bf8v*)(Ws + (cb * 32 + l31) * 256 + co);
            acc[cb] = __builtin_amdgcn_mfma_f32_32x32x16_bf16(af, bfr, acc[cb], 0, 0, 0);
        }
    }

    if (sel < 2) {
        u16* base = (sel == 0 ? qp : kp) + tg * 8192;
#pragma unroll
        for (int cb = 0; cb < 4; cb++) {
            const int colb = colbase + cb * 32;
            const float bc = bias[colb + l31];
            const int c0 = (colb >> 3) + (l31 >> 3), j0 = l31 & 7;
#pragma unroll
            for (int r = 0; r < 16; r++) {
                const int R = (r & 3) + 8 * (r >> 2) + 4 * l5;
                base[c0 * 256 + R * 8 + j0] = f2bf((acc[cb][r] + bc) * qs);
            }
        }
    } else {
        u16* base = vp + tg * 8192;
#pragma unroll
        for (int cb = 0; cb < 4; cb++) {
            const int colb = colbase + cb * 32;
            const float bc = bias[colb + l31];
            const int d0 = colb + l31;
#pragma unroll
            for (int r = 0; r < 16; r++) {
                const int R = (r & 3) + 8 * (r >> 2) + 4 * l5;
                base[(R >> 3) * 2048 + d0 * 8 + (R & 7)] = f2bf(acc[cb][r] + bc);
            }
        }
    }
}

// ---------------- flash attention: phase-fused MFMA pipeline, in-register P ----
// grid 512 (XCD-swizzled), block 256 = 4 waves x 32 q-rows. Bc=32, D=256, S=4.
// Q arrives pre-scaled by log2e/scale, so P = exp2(c0+c1) directly.
// Per iter: [vmcnt(0); barrier; DMA V(it+1),K(it+2)];
//   phase A: QK(it+1) SWAPPED (mfma(K,Q): out col = q-row) as dual 8-deep chains;
//   phase B: PV(it)+ls 18 MFMAs source-interleaved with exp2 of P(it+1);
//   tail: 8 cvt_pk + 4 permlane32_swap build pf0/pf1 A-frags IN-REGISTER.
// K prefetched 2 ahead, V 1 ahead; 1 barrier/iter.
__global__ __launch_bounds__(256, 2) void flash_attn(
    const u16* __restrict__ qp_, const u16* __restrict__ kp_, const u16* __restrict__ vp_,
    u16* __restrict__ Opb, float* __restrict__ ml)
{
    __shared__ u16 Ks[2 * 8192];   // [buf][c(32)][kv(32)][8]
    __shared__ u16 Vs[2 * 8192];   // [buf][kvc(4)][d(256)][8]

    const int tid = threadIdx.x;
    const int wave = tid >> 6, lane = tid & 63;
    const int l31 = lane & 31, l5 = lane >> 5;

    const int blk = blockIdx.x;
    const int slot = blk >> 3;
    const int g = (blk & 7) * 2 + (slot >> 5);   // (b,s) group; matches proj's XCD slabs
    const int qtile = slot & 31;
    const int b = g >> 2, s = g & 3;
    const int qbase = qtile * 128 + wave * 32;

    union { u16x8 u; bf8v v; } oneu;
#pragma unroll
    for (int j = 0; j < 8; j++) oneu.u[j] = 0x3F80;
    const bf8v ones = oneu.v;

    // Q frags from packed layout (coalesced); used as MFMA *B* operand (same
    // register layout as A: lane -> (index=l31, k=8*l5+j))
    bf8v qf[16];
    {
        const u16* qp = qp_ + (b * 128 + qtile * 4 + wave) * 8192 + l31 * 8;
#pragma unroll
        for (int kk = 0; kk < 16; kk++)
            qf[kk] = *(const bf8v*)(qp + (kk * 2 + l5) * 256);
    }

    f32x16 o[8];
#pragma unroll
    for (int i = 0; i < 8; i++)
#pragma unroll
        for (int j = 0; j < 16; j++) o[i][j] = 0.f;
    f32x16 ls;
#pragma unroll
    for (int j = 0; j < 16; j++) ls[j] = 0.f;

    const u16* kbase = kp_ + (b * 128 + s * 32) * 8192;
    const u16* vbase = vp_ + (b * 128 + s * 32) * 8192;

    // prologue: K0 (all 4 chunks FIRST so vmcnt(8) == K0 landed), then V0, K1
#pragma unroll
    for (int j = 0; j < 4; j++) {
        const int i = wave * 4 + j;
        dma16(kbase + i * 512 + lane * 8, Ks + i * 512);
    }
#pragma unroll
    for (int j = 0; j < 4; j++) {
        const int i = wave * 4 + j;
        dma16(vbase + i * 512 + lane * 8, Vs + i * 512);
    }
#pragma unroll
    for (int j = 0; j < 4; j++) {
        const int i = wave * 4 + j;
        dma16(kbase + 8192 + i * 512 + lane * 8, Ks + 8192 + i * 512);
    }
    asm volatile("s_waitcnt vmcnt(8)" ::: "memory");
    asm volatile("s_barrier" ::: "memory");

    // QK(0) swapped -> P(0) A-frags in-register
    bf8v pf0, pf1;
    {
        f32x16 c0, c1;
#pragma unroll
        for (int j = 0; j < 16; j++) { c0[j] = 0.f; c1[j] = 0.f; }
#pragma unroll
        for (int j = 0; j < 8; j++) {
            bf8v kf0 = *(const bf8v*)(Ks + (j * 2 + l5) * 256 + l31 * 8);
            c0 = __builtin_amdgcn_mfma_f32_32x32x16_bf16(kf0, qf[j], c0, 0, 0, 0);
            bf8v kf1 = *(const bf8v*)(Ks + ((8 + j) * 2 + l5) * 256 + l31 * 8);
            c1 = __builtin_amdgcn_mfma_f32_32x32x16_bf16(kf1, qf[8 + j], c1, 0, 0, 0);
        }
        float e[16];
#pragma unroll
        for (int r = 0; r < 16; r++)
            e[r] = __builtin_amdgcn_exp2f(c0[r] + c1[r]);
        u32 pA = cvtpk(e[0], e[1]), pB = cvtpk(e[2], e[3]);
        u32 pC = cvtpk(e[4], e[5]), pD = cvtpk(e[6], e[7]);
        plswap(pA, pC); plswap(pB, pD);
        u32 pE = cvtpk(e[8], e[9]),  pF = cvtpk(e[10], e[11]);
        u32 pG = cvtpk(e[12], e[13]), pH = cvtpk(e[14], e[15]);
        plswap(pE, pG); plswap(pF, pH);
        union { uint4 u; bf8v v; } u0, u1;
        u0.u = (uint4){pA, pB, pC, pD};
        u1.u = (uint4){pE, pF, pG, pH};
        pf0 = u0.v; pf1 = u1.v;
    }

#pragma unroll 1
    for (int it = 0; it < 31; it++) {
        const int buf = it & 1;
        asm volatile("s_waitcnt vmcnt(0)" ::: "memory");  // V(it), K(it+1) landed
        asm volatile("s_barrier" ::: "memory");           // visible; old bufs free
        {
            const u16* vt_ = vbase + (it + 1) * 8192;
#pragma unroll
            for (int j = 0; j < 4; j++) {
                const int i = wave * 4 + j;
                dma16(vt_ + i * 512 + lane * 8, Vs + (buf ^ 1) * 8192 + i * 512);
            }
            if (it < 30) {
                const u16* kt_ = kbase + (it + 2) * 8192;
#pragma unroll
                for (int j = 0; j < 4; j++) {
                    const int i = wave * 4 + j;
                    dma16(kt_ + i * 512 + lane * 8, Ks + buf * 8192 + i * 512);
                }
            }
        }
        // ---- phase A: QK(it+1) swapped, dual 8-deep accumulator chains
        const u16* Kb_ = Ks + (buf ^ 1) * 8192;
        f32x16 c0, c1;
#pragma unroll
        for (int j = 0; j < 16; j++) { c0[j] = 0.f; c1[j] = 0.f; }
#pragma unroll
        for (int j = 0; j < 8; j++) {
            bf8v kf0 = *(const bf8v*)(Kb_ + (j * 2 + l5) * 256 + l31 * 8);
            c0 = __builtin_amdgcn_mfma_f32_32x32x16_bf16(kf0, qf[j], c0, 0, 0, 0);
            bf8v kf1 = *(const bf8v*)(Kb_ + ((8 + j) * 2 + l5) * 256 + l31 * 8);
            c1 = __builtin_amdgcn_mfma_f32_32x32x16_bf16(kf1, qf[8 + j], c1, 0, 0, 0);
        }
        // ---- phase B: PV(it)+ls MFMAs interleaved with exp2 of P(it+1)
        const u16* Vb_ = Vs + buf * 8192;
        ls = __builtin_amdgcn_mfma_f32_32x32x16_bf16(pf0, ones, ls, 0, 0, 0);
        ls = __builtin_amdgcn_mfma_f32_32x32x16_bf16(pf1, ones, ls, 0, 0, 0);
        float e[16];
#pragma unroll
        for (int j = 0; j < 8; j++) {
            bf8v vf0 = *(const bf8v*)(Vb_ + (l5 * 256 + j * 32 + l31) * 8);
            o[j] = __builtin_amdgcn_mfma_f32_32x32x16_bf16(pf0, vf0, o[j], 0, 0, 0);
            e[2 * j] = __builtin_amdgcn_exp2f(c0[2 * j] + c1[2 * j]);
            bf8v vf1 = *(const bf8v*)(Vb_ + ((2 + l5) * 256 + j * 32 + l31) * 8);
            o[j] = __builtin_amdgcn_mfma_f32_32x32x16_bf16(pf1, vf1, o[j], 0, 0, 0);
            e[2 * j + 1] = __builtin_amdgcn_exp2f(c0[2 * j + 1] + c1[2 * j + 1]);
        }
        // ---- tail: build P(it+1) A-frags in-register (no LDS roundtrip)
        {
            u32 pA = cvtpk(e[0], e[1]), pB = cvtpk(e[2], e[3]);
            u32 pC = cvtpk(e[4], e[5]), pD = cvtpk(e[6], e[7]);
            plswap(pA, pC); plswap(pB, pD);
            u32 pE = cvtpk(e[8], e[9]),  pF = cvtpk(e[10], e[11]);
            u32 pG = cvtpk(e[12], e[13]), pH = cvtpk(e[14], e[15]);
            plswap(pE, pG); plswap(pF, pH);
            union { uint4 u; bf8v v; } u0, u1;
            u0.u = (uint4){pA, pB, pC, pD};
            u1.u = (uint4){pE, pF, pG, pH};
            pf0 = u0.v; pf1 = u1.v;
        }
    }

    // tail: PV(31)
    asm volatile("s_waitcnt vmcnt(0)" ::: "memory");
    asm volatile("s_barrier" ::: "memory");
    {
        const u16* Vb_ = Vs + 8192;   // V(31) in buf 1
        ls = __builtin_amdgcn_mfma_f32_32x32x16_bf16(pf0, ones, ls, 0, 0, 0);
        ls = __builtin_amdgcn_mfma_f32_32x32x16_bf16(pf1, ones, ls, 0, 0, 0);
#pragma unroll
        for (int j = 0; j < 8; j++) {
            bf8v vf0 = *(const bf8v*)(Vb_ + (l5 * 256 + j * 32 + l31) * 8);
            o[j] = __builtin_amdgcn_mfma_f32_32x32x16_bf16(pf0, vf0, o[j], 0, 0, 0);
            bf8v vf1 = *(const bf8v*)(Vb_ + ((2 + l5) * 256 + j * 32 + l31) * 8);
            o[j] = __builtin_amdgcn_mfma_f32_32x32x16_bf16(pf1, vf1, o[j], 0, 0, 0);
        }
    }

    // epilogue: unnormalized O in bf16 + l (m==0 everywhere)
    const int rowg = s * 16384 + b * 4096 + qbase;
    u16* ob = Opb + (size_t)rowg * 256;
#pragma unroll
    for (int nb = 0; nb < 8; nb++)
#pragma unroll
        for (int r = 0; r < 16; r++) {
            const int R = (r & 3) + 8 * (r >> 2) + 4 * l5;
            ob[R * 256 + nb * 32 + l31] = f2bf(o[nb][r]);
        }
    if (l31 == 0)
#pragma unroll
        for (int r = 0; r < 16; r++) {
            const int R = (r & 3) + 8 * (r >> 2) + 4 * l5;
            ml[rowg + R] = ls[r];
        }
}

// ---------------- combine partials (m==0: denom = sum of l) ----------------
__global__ __launch_bounds__(256) void combine(
    const u16* __restrict__ Opb, const float* __restrict__ ml, float* __restrict__ out)
{
    const int row = blockIdx.x * 4 + (threadIdx.x >> 6);
    const int lane = threadIdx.x & 63;
    const float denom = ml[row] + ml[16384 + row] + ml[32768 + row] + ml[49152 + row];
    float4 acc = {0.f, 0.f, 0.f, 0.f};
#pragma unroll
    for (int si = 0; si < 4; si++) {
        ushort4 v = *(const ushort4*)(Opb + ((size_t)si * 16384 + row) * 256 + lane * 4);
        acc.x += bf2f(v.x); acc.y += bf2f(v.y);
        acc.z += bf2f(v.z); acc.w += bf2f(v.w);
    }
    const float inv = 1.0f / denom;
    acc.x *= inv; acc.y *= inv; acc.z *= inv; acc.w *= inv;
    *((float4*)(out + (size_t)row * 256) + lane) = acc;
}

extern "C" void kernel_launch(void* const* d_in, const int* in_sizes, int n_in,
                              void* d_out, int out_size, void* d_ws, size_t ws_size,
                              hipStream_t stream) {
    const float* x     = (const float*)d_in[0];
    const float* Wq    = (const float*)d_in[1];
    const float* bq    = (const float*)d_in[2];
    const float* Wk    = (const float*)d_in[3];
    const float* bk    = (const float*)d_in[4];
    const float* Wv    = (const float*)d_in[5];
    const float* bv    = (const float*)d_in[6];
    const float* scale = (const float*)d_in[7];
    float* out = (float*)d_out;

    char* ws = (char*)d_ws;
    u16* xp   = (u16*)ws;                        // 8 MB packed x
    u16* qp   = (u16*)(ws + (8u  << 20));        // 8 MB packed Q (pre-scaled by log2e/scale)
    u16* kp   = (u16*)(ws + (16u << 20));        // 8 MB packed K
    u16* vp   = (u16*)(ws + (24u << 20));        // 8 MB packed V
    u16* wall = (u16*)(ws + (32u << 20));        // 3 x 128 KB bf16 W (swizzled)
    u16* Opb  = (u16*)(ws + (34u << 20));        // 4 x 8 MB bf16 partials
    float* ml = (float*)(ws + (66u << 20));      // 4 x 64 KB l-sums

    cvt_all<<<2144, 256, 0, stream>>>(x, Wq, Wk, Wv, xp, wall);
    qkv_proj<<<768, 256, 0, stream>>>(xp, wall, bq, bk, bv, scale, qp, kp, vp);
    flash_attn<<<512, 256, 0, stream>>>(qp, kp, vp, Opb, ml);
    combine<<<4096, 256, 0, stream>>>(Opb, ml, out);
}